// Round 15
// baseline (224.829 us; speedup 1.0000x reference)
//
#include <hip/hip_runtime.h>

#define NB 16384
#define ND 512
#define NH 128
#define NHH 256
#define NG 18
#define SLOTS 8960   // per-genre position slack (18 x 140 blocks x 64)

typedef short s8v __attribute__((ext_vector_type(8)));
typedef __bf16 bf8v __attribute__((ext_vector_type(8)));
typedef float f16v __attribute__((ext_vector_type(16)));
typedef unsigned int u4v __attribute__((ext_vector_type(4)));

static __device__ __forceinline__ unsigned short f2bf(float f) {
  unsigned int u = __builtin_bit_cast(unsigned int, f);
  u += 0x7FFFu + ((u >> 16) & 1u);
  return (unsigned short)(u >> 16);
}

static __device__ __forceinline__ float bf2f(unsigned short u) {
  unsigned int v = ((unsigned int)u) << 16;
  return __builtin_bit_cast(float, v);
}

static __device__ __forceinline__ unsigned pk2(float a, float b) {
  return (unsigned)f2bf(a) | ((unsigned)f2bf(b) << 16);
}

static __device__ __forceinline__ f16v mfma32(s8v a, s8v b, f16v c) {
  return __builtin_amdgcn_mfma_f32_32x32x16_bf16(
      __builtin_bit_cast(bf8v, a), __builtin_bit_cast(bf8v, b), c, 0, 0, 0);
}

static __device__ __forceinline__ f16v zf16() {
  f16v v;
#pragma unroll
  for (int i = 0; i < 16; ++i) v[i] = 0.f;
  return v;
}

// per-ks compile-time swizzle XOR for fragment-linear H1/H2 reads
#define KM(ks) (((((ks) & 1) << 5)) | ((((ks) >> 1) & 1) << 6))

// ============================ shared prep kernels ============================

// pack W [G][K][N] f32 -> B-fragment-linear bf16 for mfma_32x32x16
__global__ __launch_bounds__(256) void k_pack(const float* __restrict__ in,
                                              unsigned short* __restrict__ out,
                                              int K, int N) {
  const int g = blockIdx.y;
  const int c = blockIdx.x * 256 + threadIdx.x;
  const int nk = K >> 4;
  const int l = c & 63;
  const int t = c >> 6;
  const int nt = t / nk;
  const int ks = t - nt * nk;
  const int k0 = (ks << 4) + ((l >> 5) << 3);
  const int col = (nt << 5) + (l & 31);
  const float* ip = in + (size_t)g * K * N + (size_t)k0 * N + col;
  u4v pk;
#pragma unroll
  for (int j = 0; j < 4; ++j)
    pk[j] = pk2(ip[(size_t)(2 * j) * N], ip[(size_t)(2 * j + 1) * N]);
  *(u4v*)(out + (size_t)g * K * N + ((size_t)c << 3)) = pk;
}

// pack Wa [512][18] -> fragment stream [32 ks][64 lane][8], cols >= 18 zeroed
__global__ __launch_bounds__(256) void k_packa(const float* __restrict__ wa,
                                               unsigned short* __restrict__ wap) {
  const int t = blockIdx.x * 256 + threadIdx.x;  // 0..2047
  const int ks = t >> 6, l = t & 63;
  const int col = l & 31;
  const int k0 = (ks << 4) + ((l >> 5) << 3);
  u4v pk;
  if (col < 18) {
    const float* ip = wa + (size_t)k0 * NG + col;
#pragma unroll
    for (int j = 0; j < 4; ++j)
      pk[j] = pk2(ip[(size_t)(2 * j) * NG], ip[(size_t)(2 * j + 1) * NG]);
  } else {
    pk[0] = pk[1] = pk[2] = pk[3] = 0u;
  }
  *(u4v*)(wap + ((size_t)t << 3)) = pk;
}

// ============================ sparse-path kernels ============================

// Wa [512][18] -> WaT [18][512] f32
__global__ __launch_bounds__(256) void k_wat(const float* __restrict__ wa,
                                             float* __restrict__ wat) {
  int tid = blockIdx.x * 256 + threadIdx.x;
  if (tid < NG * ND) {
    int g = tid >> 9, d = tid & (ND - 1);
    wat[tid] = wa[d * NG + g];
  }
}

// attention weights w[B,G] = softmax(X@Wa+ba) * gv  (0 where gv==0)
__global__ __launch_bounds__(256) void k_attn(const float* __restrict__ X,
                                              const float* __restrict__ GV,
                                              const float* __restrict__ wat,
                                              const float* __restrict__ ba,
                                              float* __restrict__ w) {
  __shared__ float wl[NG * ND];
  const int tid = threadIdx.x;
  for (int i = tid; i < NG * ND; i += 256) wl[i] = wat[i];
  __syncthreads();
  const int lane = tid & 63;
  const int row = (blockIdx.x << 2) + (tid >> 6);
  const float* xr = X + (size_t)row * ND + (lane << 3);
  float x[8];
  {
    float4 a = *(const float4*)xr;
    float4 b = *(const float4*)(xr + 4);
    x[0] = a.x; x[1] = a.y; x[2] = a.z; x[3] = a.w;
    x[4] = b.x; x[5] = b.y; x[6] = b.z; x[7] = b.w;
  }
  float lg[NG];
#pragma unroll
  for (int g = 0; g < NG; ++g) {
    const float* wr = wl + g * ND + (lane << 3);
    float s = 0.f;
#pragma unroll
    for (int j = 0; j < 8; ++j) s += x[j] * wr[j];
    lg[g] = s;
  }
#pragma unroll
  for (int off = 32; off > 0; off >>= 1) {
#pragma unroll
    for (int g = 0; g < NG; ++g) lg[g] += __shfl_xor(lg[g], off);
  }
  float m = -3.4e38f;
#pragma unroll
  for (int g = 0; g < NG; ++g) { lg[g] += ba[g]; m = fmaxf(m, lg[g]); }
  float s = 0.f;
#pragma unroll
  for (int g = 0; g < NG; ++g) { lg[g] = expf(lg[g] - m); s += lg[g]; }
  float inv = 1.f / s;
  if (lane < NG) {
    float gv = GV[(size_t)row * NG + lane];
    w[(size_t)row * NG + lane] = gv > 0.f ? lg[lane] * inv * gv : 0.f;
  }
}

// per-chunk (256 rows) per-genre active counts
__global__ __launch_bounds__(256) void k_count(const float* __restrict__ wdn,
                                               int* __restrict__ ccnt) {
  __shared__ int wc[4];
  const int t = threadIdx.x, blk = blockIdx.x;
  const int row = (blk << 8) + t;
  const int wv = t >> 6, lane = t & 63;
  for (int g = 0; g < NG; ++g) {
    bool act = wdn[(size_t)row * NG + g] > 0.f;
    unsigned long long m = __ballot(act);
    if (lane == 0) wc[wv] = __popcll(m);
    __syncthreads();
    if (t == 0) ccnt[g * 64 + blk] = wc[0] + wc[1] + wc[2] + wc[3];
    __syncthreads();
  }
}

// exclusive scan of chunk counts -> chunk offsets + totals
__global__ __launch_bounds__(32) void k_scan(const int* __restrict__ ccnt,
                                             int* __restrict__ coff,
                                             int* __restrict__ cnt) {
  int g = threadIdx.x;
  if (g < NG) {
    int off = 0;
    for (int c = 0; c < 64; ++c) { coff[g * 64 + c] = off; off += ccnt[g * 64 + c]; }
    cnt[g] = off;
  }
}

// emit compacted per-genre lists: idx/wv and inverse map pos[b][g]
__global__ __launch_bounds__(256) void k_emit(const float* __restrict__ wdn,
                                              const int* __restrict__ coff,
                                              int* __restrict__ idx,
                                              float* __restrict__ wvv,
                                              int* __restrict__ pos) {
  __shared__ int wc[4];
  const int t = threadIdx.x, blk = blockIdx.x;
  const int row = (blk << 8) + t;
  const int wv = t >> 6, lane = t & 63;
  for (int g = 0; g < NG; ++g) {
    float w = wdn[(size_t)row * NG + g];
    bool act = w > 0.f;
    unsigned long long m = __ballot(act);
    if (lane == 0) wc[wv] = __popcll(m);
    __syncthreads();
    int base = coff[g * 64 + blk];
#pragma unroll
    for (int q = 0; q < 4; ++q)
      if (q < wv) base += wc[q];
    int rank = __popcll(m & ((1ull << lane) - 1ull));
    int p = base + rank;
    if (act && p < SLOTS) {
      idx[g * SLOTS + p] = row;
      wvv[g * SLOTS + p] = w;
      pos[(size_t)row * NG + g] = p;
    } else {
      pos[(size_t)row * NG + g] = -1;
    }
    __syncthreads();
  }
}

// experts on gathered rows of ONE genre. block = (chunk of 64 positions, genre).
__global__ __launch_bounds__(512, 1) void k_expert(
    const float* __restrict__ X,
    const int* __restrict__ cnt,
    const int* __restrict__ idx,
    const float* __restrict__ wvv,
    const unsigned short* __restrict__ w1p,
    const unsigned short* __restrict__ w2p,
    const unsigned short* __restrict__ w3p,
    const float* __restrict__ b1, const float* __restrict__ b2,
    const float* __restrict__ b3,
    unsigned short* __restrict__ h3g) {
  __shared__ __align__(16) char smem[115712];
  char* const XT = smem;                      // [2][32][1024] = 64KB linear
  char* const H1 = smem + 65536;              // 32KB swz
  char* const H2 = smem + 98304;              // 16KB swz
  int* const idxl = (int*)(smem + 114688);    // [64]
  float* const wvl = (float*)(smem + 114944); // [64]

  const int g = blockIdx.y;
  const int p0 = blockIdx.x << 6;
  const int cg = cnt[g];
  if (p0 >= cg) return;

  const int tid = threadIdx.x;
  const int wid = tid >> 6, lane = tid & 63;
  const int l31 = lane & 31, lh = lane >> 5;
  const int lb = (lane << 4) ^ (lh << 4);

  if (tid < 64) {
    int p = p0 + tid;
    int pc = min(p, cg - 1);
    idxl[tid] = idx[g * SLOTS + pc];
    wvl[tid] = (p < cg) ? wvv[g * SLOTS + pc] : 0.f;
  }
  // GEMM1 B queue preload (independent of idxl; drains under barriers)
  const unsigned short* const bp1 =
      w1p + (size_t)g * 131072 + (wid << 14) + (lane << 3);
  s8v bq[8];
#pragma unroll
  for (int i = 0; i < 8; ++i) bq[i] = *(const s8v*)(bp1 + (i << 9));
  __syncthreads();  // idxl ready

  // stage gathered XT (f32 -> bf16) fragment-linear
#pragma unroll
  for (int i = 0; i < 8; ++i) {
    int ck = (i << 9) + tid;
    int mt = ck >> 11, ks = (ck >> 6) & 31, l = ck & 63;
    int grow = idxl[(mt << 5) + (l & 31)];
    int c8 = (ks << 1) + (l >> 5);
    const float* xp = X + ((size_t)grow << 9) + (c8 << 3);
    float4 xa = *(const float4*)xp;
    float4 xc = *(const float4*)(xp + 4);
    u4v p;
    p[0] = pk2(xa.x, xa.y); p[1] = pk2(xa.z, xa.w);
    p[2] = pk2(xc.x, xc.y); p[3] = pk2(xc.z, xc.w);
    *(u4v*)(XT + (ck << 4)) = p;
  }

  const int nt2 = wid & 3, mt2 = wid >> 2;
  const unsigned short* const bp2 =
      w2p + ((size_t)g << 15) + (nt2 << 13) + (lane << 3);
  const unsigned short* const bp3 =
      w3p + ((size_t)g << 14) + (nt2 << 12) + (lane << 3);

  const int gc1 = (wid << 5) + l31;
  const int gc2 = (nt2 << 5) + l31;
  const int cb1 = ((gc1 >> 4) << 10) + (((gc1 >> 3) & 1) << 9) + ((gc1 & 7) << 1);
  const int cb2 = ((gc2 >> 4) << 10) + (((gc2 >> 3) & 1) << 9) + ((gc2 & 7) << 1);
  const int m1 = (((cb1 >> 9) & 1) << 4) | (((cb1 >> 10) & 1) << 5) | (((cb1 >> 11) & 1) << 6);
  const int m2 = (((cb2 >> 9) & 1) << 4) | (((cb2 >> 10) & 1) << 5) | (((cb2 >> 11) & 1) << 6);

  __syncthreads();  // XT staged

  // ---------- GEMM1: h1 = relu(X @ W1[g] + b1[g])  [64,256] ----------
  f16v accA0 = zf16(), accA1 = zf16(), accB0 = zf16(), accB1 = zf16();
#pragma unroll
  for (int ks = 0; ks < 32; ++ks) {
    s8v bn;
    if (ks < 24) bn = *(const s8v*)(bp1 + ((ks + 8) << 9));
    s8v a0 = *(const s8v*)(XT + (ks << 10) + (lane << 4));
    s8v a1 = *(const s8v*)(XT + 32768 + (ks << 10) + (lane << 4));
    if (ks & 1) {
      accA1 = mfma32(a0, bq[ks & 7], accA1);
      accB1 = mfma32(a1, bq[ks & 7], accB1);
    } else {
      accA0 = mfma32(a0, bq[ks & 7], accA0);
      accB0 = mfma32(a1, bq[ks & 7], accB0);
    }
    if (ks < 24) bq[ks & 7] = bn;
  }
  {
    const float bv1 = b1[(g << 8) + gc1];
#pragma unroll
    for (int r = 0; r < 16; ++r) {
      const int rl = (r & 3) + ((r >> 2) << 3) + (lh << 2);
      const int boff = (cb1 + (rl << 4)) ^ m1;
      *(unsigned short*)(H1 + boff) = f2bf(fmaxf(accA0[r] + accA1[r] + bv1, 0.f));
      *(unsigned short*)(H1 + 16384 + boff) = f2bf(fmaxf(accB0[r] + accB1[r] + bv1, 0.f));
    }
  }
  // hoist full GEMM2 B + bias (completes inside barrier drain)
  s8v b2f[16];
#pragma unroll
  for (int k = 0; k < 16; ++k) b2f[k] = *(const s8v*)(bp2 + (k << 9));
  const float bv2 = b2[(g << 7) + gc2];
  __syncthreads();

  // ---------- GEMM2: h2 = relu(h1 @ W2[g] + b2[g])  [64,128] ----------
  f16v acc2a = zf16(), acc2b = zf16();
#pragma unroll
  for (int i = 0; i < 16; ++i) {
    s8v a2 = *(const s8v*)(H1 + (mt2 << 14) + (((i << 10) + lb) ^ KM(i)));
    if (i & 1) acc2b = mfma32(a2, b2f[i], acc2b);
    else       acc2a = mfma32(a2, b2f[i], acc2a);
  }
#pragma unroll
  for (int r = 0; r < 16; ++r) {
    const int rl = (r & 3) + ((r >> 2) << 3) + (lh << 2);
    float v = fmaxf(acc2a[r] + acc2b[r] + bv2, 0.f);
    *(unsigned short*)(H2 + (mt2 << 13) + ((cb2 + (rl << 4)) ^ m2)) = f2bf(v);
  }
  // hoist GEMM3 B + bias
  s8v b3f[8];
#pragma unroll
  for (int k = 0; k < 8; ++k) b3f[k] = *(const s8v*)(bp3 + (k << 9));
  const float bv3 = b3[(g << 7) + gc2];
  __syncthreads();

  // ---------- GEMM3 + weighted write to h3g ----------
  f16v acc3a = zf16(), acc3b = zf16();
#pragma unroll
  for (int i = 0; i < 8; ++i) {
    s8v a3 = *(const s8v*)(H2 + (mt2 << 13) + (((i << 10) + lb) ^ KM(i)));
    if (i & 1) acc3b = mfma32(a3, b3f[i], acc3b);
    else       acc3a = mfma32(a3, b3f[i], acc3a);
  }
#pragma unroll
  for (int r = 0; r < 16; ++r) {
    const int rl = (r & 3) + ((r >> 2) << 3) + (lh << 2);
    const int rowl = (mt2 << 5) + rl;
    float v = wvl[rowl] * (acc3a[r] + acc3b[r] + bv3);
    h3g[((size_t)g * SLOTS + p0 + rowl) * 128 + (nt2 << 5) + l31] = f2bf(v);
  }
}

// aggregation: gather-sum refinements + out = relu([X|ref] @ Wagg + bagg)
__global__ __launch_bounds__(512, 1) void k_agg(
    const float* __restrict__ X,
    const int* __restrict__ pos,
    const unsigned short* __restrict__ h3g,
    const unsigned short* __restrict__ w4p,
    const float* __restrict__ bagg,
    float* __restrict__ out) {
  __shared__ __align__(16) char smem[87040];
  char* const XT = smem;                      // [2][32][1024] = 64KB linear
  char* const REF = smem + 65536;             // [2][8][1024] = 16KB linear A-frag
  int* const posl = (int*)(smem + 81920);     // [64][20]

  const int tid = threadIdx.x;
  const int row0 = blockIdx.x << 6;
  const int wid = tid >> 6, lane = tid & 63;
  const int l31 = lane & 31, lh = lane >> 5;

  // stage XT (f32 -> bf16) fragment-linear
#pragma unroll
  for (int i = 0; i < 8; ++i) {
    int ck = (i << 9) + tid;
    int mt = ck >> 11, ks = (ck >> 6) & 31, l = ck & 63;
    int grow = row0 + (mt << 5) + (l & 31);
    int c8 = (ks << 1) + (l >> 5);
    const float* xp = X + ((size_t)grow << 9) + (c8 << 3);
    float4 xa = *(const float4*)xp;
    float4 xc = *(const float4*)(xp + 4);
    u4v p;
    p[0] = pk2(xa.x, xa.y); p[1] = pk2(xa.z, xa.w);
    p[2] = pk2(xc.x, xc.y); p[3] = pk2(xc.z, xc.w);
    *(u4v*)(XT + (ck << 4)) = p;
  }
  for (int i = tid; i < 64 * NG; i += 512) {
    int r = i / NG, g = i - r * NG;
    posl[r * 20 + g] = pos[(size_t)(row0 + r) * NG + g];
  }
  // GEMM4 dual B queue preload
  const unsigned short* const bp4a = w4p + (size_t)wid * 20480 + (lane << 3);
  const unsigned short* const bp4b = w4p + (size_t)(wid + 8) * 20480 + (lane << 3);
  s8v bq4[4][2];
#pragma unroll
  for (int k = 0; k < 4; ++k) {
    bq4[k][0] = *(const s8v*)(bp4a + (k << 9));
    bq4[k][1] = *(const s8v*)(bp4b + (k << 9));
  }
  __syncthreads();

  // gather-sum ref rows into REF (A-fragment linear layout)
#pragma unroll
  for (int it = 0; it < 2; ++it) {
    int item = (it << 9) + tid;               // 0..1023
    int row = item >> 4, c = item & 15;
    float a8[8];
#pragma unroll
    for (int j = 0; j < 8; ++j) a8[j] = 0.f;
    for (int g = 0; g < NG; ++g) {
      int p = posl[row * 20 + g];
      if (p >= 0) {
        u4v h = *(const u4v*)(h3g + ((size_t)g * SLOTS + p) * 128 + (c << 3));
#pragma unroll
        for (int j = 0; j < 4; ++j) {
          a8[2 * j] += bf2f((unsigned short)(h[j] & 0xFFFFu));
          a8[2 * j + 1] += bf2f((unsigned short)(h[j] >> 16));
        }
      }
    }
    u4v pkv;
#pragma unroll
    for (int j = 0; j < 4; ++j) pkv[j] = pk2(a8[2 * j], a8[2 * j + 1]);
    int addr = ((row >> 5) << 13) + ((c >> 1) << 10) +
               ((((c & 1) << 5) + (row & 31)) << 4);
    *(u4v*)(REF + addr) = pkv;
  }
  __syncthreads();

  // ---------- GEMM4: out = relu([X | ref] @ Wagg + bagg)  [64,512] ----------
  f16v acc4[2][2];
  acc4[0][0] = zf16(); acc4[0][1] = zf16();
  acc4[1][0] = zf16(); acc4[1][1] = zf16();
#pragma unroll
  for (int ks = 0; ks < 40; ++ks) {
    s8v bn0, bn1;
    if (ks < 36) {
      bn0 = *(const s8v*)(bp4a + ((ks + 4) << 9));
      bn1 = *(const s8v*)(bp4b + ((ks + 4) << 9));
    }
    s8v a0, a1;
    if (ks < 32) {
      a0 = *(const s8v*)(XT + (ks << 10) + (lane << 4));
      a1 = *(const s8v*)(XT + 32768 + (ks << 10) + (lane << 4));
    } else {
      const int hk = ks - 32;
      a0 = *(const s8v*)(REF + (hk << 10) + (lane << 4));
      a1 = *(const s8v*)(REF + 8192 + (hk << 10) + (lane << 4));
    }
    acc4[0][0] = mfma32(a0, bq4[ks & 3][0], acc4[0][0]);
    acc4[1][0] = mfma32(a1, bq4[ks & 3][0], acc4[1][0]);
    acc4[0][1] = mfma32(a0, bq4[ks & 3][1], acc4[0][1]);
    acc4[1][1] = mfma32(a1, bq4[ks & 3][1], acc4[1][1]);
    if (ks < 36) { bq4[ks & 3][0] = bn0; bq4[ks & 3][1] = bn1; }
  }
  {
    const float bv4a = bagg[(wid << 5) + l31];
    const float bv4b = bagg[((wid + 8) << 5) + l31];
#pragma unroll
    for (int mt = 0; mt < 2; ++mt)
#pragma unroll
      for (int r = 0; r < 16; ++r) {
        const int rl = (r & 3) + ((r >> 2) << 3) + (lh << 2);
        const size_t rbase = (size_t)(row0 + (mt << 5) + rl) << 9;
        out[rbase + (wid << 5) + l31] = fmaxf(acc4[mt][0][r] + bv4a, 0.f);
        out[rbase + ((wid + 8) << 5) + l31] = fmaxf(acc4[mt][1][r] + bv4b, 0.f);
      }
  }
}

// ===================== dense fallback (R14 k_main, unchanged) ================

__global__ __launch_bounds__(512, 1) void k_main(
    const float* __restrict__ X, const float* __restrict__ GV,
    const unsigned short* __restrict__ w1p, const unsigned short* __restrict__ w2p,
    const unsigned short* __restrict__ w3p, const unsigned short* __restrict__ w4p,
    const unsigned short* __restrict__ wap,
    const float* __restrict__ b1, const float* __restrict__ b2,
    const float* __restrict__ b3, const float* __restrict__ bagg,
    const float* __restrict__ ba, float* __restrict__ out) {
  __shared__ __align__(16) char smem[128256];
  char* const XT = smem;
  char* const H1 = smem + 65536;
  char* const H2 = smem + 98304;
  float* const WL = (float*)(smem + 114688);
  float* const Lsm = (float*)(smem + 119808);

  const int tid = threadIdx.x;
  const int row0 = blockIdx.x << 6;
  const int wid = tid >> 6, lane = tid & 63;
  const int l31 = lane & 31, lh = lane >> 5;
  const int lb = (lane << 4) ^ (lh << 4);

#pragma unroll
  for (int i = 0; i < 8; ++i) {
    int ck = (i << 9) + tid;
    int mt = ck >> 11, ks = (ck >> 6) & 31, l = ck & 63;
    int grow = row0 + (mt << 5) + (l & 31);
    int c8 = (ks << 1) + (l >> 5);
    const float* xp = X + ((size_t)grow << 9) + (c8 << 3);
    float4 xa = *(const float4*)xp;
    float4 xc = *(const float4*)(xp + 4);
    u4v p;
    p[0] = pk2(xa.x, xa.y); p[1] = pk2(xa.z, xa.w);
    p[2] = pk2(xc.x, xc.y); p[3] = pk2(xc.z, xc.w);
    *(u4v*)(XT + (ck << 4)) = p;
  }

  const unsigned short* const bp1 = w1p + (wid << 14) + (lane << 3);
  s8v bq1[8];
#pragma unroll
  for (int i = 0; i < 8; ++i) bq1[i] = *(const s8v*)(bp1 + (i << 9));
  __syncthreads();

  if (wid < 2) {
    f16v accL = zf16();
    const unsigned short* const bpa = wap + (lane << 3);
#pragma unroll
    for (int ks = 0; ks < 32; ++ks) {
      s8v a = *(const s8v*)(XT + (wid << 15) + (ks << 10) + (lane << 4));
      s8v b = *(const s8v*)(bpa + (ks << 9));
      accL = mfma32(a, b, accL);
    }
    const float bav = (l31 < NG) ? ba[l31] : 0.f;
#pragma unroll
    for (int r = 0; r < 16; ++r) {
      const int rl = (r & 3) + ((r >> 2) << 3) + (lh << 2);
      Lsm[((wid << 5) + rl) * 33 + l31] = accL[r] + bav;
    }
  }
  __syncthreads();

  if (lane < 8) {
    const int row = (wid << 3) + lane;
    float lg[NG], mx = -3.4e38f;
#pragma unroll
    for (int q = 0; q < NG; ++q) { lg[q] = Lsm[row * 33 + q]; mx = fmaxf(mx, lg[q]); }
    float s = 0.f;
#pragma unroll
    for (int q = 0; q < NG; ++q) { lg[q] = expf(lg[q] - mx); s += lg[q]; }
    const float inv = 1.f / s;
#pragma unroll
    for (int q = 0; q < NG; ++q) {
      float gv = GV[(size_t)(row0 + row) * NG + q];
      WL[row * 20 + q] = gv > 0.f ? lg[q] * inv * gv : 0.f;
    }
  }

  const int nt2 = wid & 3, mt2 = wid >> 2;
  const unsigned short* const bp2 = w2p + (nt2 << 13) + (lane << 3);
  const unsigned short* const bp3 = w3p + (nt2 << 12) + (lane << 3);
  const unsigned short* const bp4a = w4p + (size_t)wid * 20480 + (lane << 3);
  const unsigned short* const bp4b = w4p + (size_t)(wid + 8) * 20480 + (lane << 3);

  const int gc1 = (wid << 5) + l31;
  const int gc2 = (nt2 << 5) + l31;
  const int cb1 = ((gc1 >> 4) << 10) + (((gc1 >> 3) & 1) << 9) + ((gc1 & 7) << 1);
  const int cb2 = ((gc2 >> 4) << 10) + (((gc2 >> 3) & 1) << 9) + ((gc2 & 7) << 1);
  const int m1 = (((cb1 >> 9) & 1) << 4) | (((cb1 >> 10) & 1) << 5) | (((cb1 >> 11) & 1) << 6);
  const int m2 = (((cb2 >> 9) & 1) << 4) | (((cb2 >> 10) & 1) << 5) | (((cb2 >> 11) & 1) << 6);

  f16v racc = zf16();
  s8v b2f[16];
  float bv2;

  {
    f16v accA0 = zf16(), accA1 = zf16(), accB0 = zf16(), accB1 = zf16();
#pragma unroll
    for (int ks = 0; ks < 32; ++ks) {
      s8v bn;
      {
        size_t off = (ks < 24) ? (size_t)((ks + 8) << 9)
                               : (size_t)131072 + ((ks - 24) << 9);
        bn = *(const s8v*)(bp1 + off);
      }
      s8v a0 = *(const s8v*)(XT + (ks << 10) + (lane << 4));
      s8v a1 = *(const s8v*)(XT + 32768 + (ks << 10) + (lane << 4));
      if (ks & 1) {
        accA1 = mfma32(a0, bq1[ks & 7], accA1);
        accB1 = mfma32(a1, bq1[ks & 7], accB1);
      } else {
        accA0 = mfma32(a0, bq1[ks & 7], accA0);
        accB0 = mfma32(a1, bq1[ks & 7], accB0);
      }
      bq1[ks & 7] = bn;
    }
    const float bv1 = b1[gc1];
#pragma unroll
    for (int r = 0; r < 16; ++r) {
      const int rl = (r & 3) + ((r >> 2) << 3) + (lh << 2);
      const int boff = (cb1 + (rl << 4)) ^ m1;
      *(unsigned short*)(H1 + boff) = f2bf(fmaxf(accA0[r] + accA1[r] + bv1, 0.f));
      *(unsigned short*)(H1 + 16384 + boff) = f2bf(fmaxf(accB0[r] + accB1[r] + bv1, 0.f));
    }
#pragma unroll
    for (int k = 0; k < 16; ++k) b2f[k] = *(const s8v*)(bp2 + (k << 9));
    bv2 = b2[gc2];
  }
  __syncthreads();

  for (int g = 0; g < NG - 1; ++g) {
    const unsigned short* const bp1gn = bp1 + (size_t)(g + 1) * 131072;
    const unsigned short* const bp1gnn = bp1 + (size_t)(g + 2) * 131072;
    const unsigned short* const bp3g = bp3 + ((size_t)g << 14);
    const bool refill2 = (g + 2 < NG);

    f16v acc2a = zf16(), acc2b = zf16();
    f16v accA = zf16(), accB = zf16();
#pragma unroll
    for (int i = 0; i < 16; ++i) {
      s8v a2 = *(const s8v*)(H1 + (mt2 << 14) + (((i << 10) + lb) ^ KM(i)));
      s8v a0 = *(const s8v*)(XT + (i << 10) + (lane << 4));
      s8v a1 = *(const s8v*)(XT + 32768 + (i << 10) + (lane << 4));
      s8v cb = bq1[i & 7];
      bq1[i & 7] = *(const s8v*)(bp1gn + ((i + 8) << 9));
      if (i & 1) acc2b = mfma32(a2, b2f[i], acc2b);
      else       acc2a = mfma32(a2, b2f[i], acc2a);
      accA = mfma32(a0, cb, accA);
      accB = mfma32(a1, cb, accB);
    }
    s8v b3f[8];
#pragma unroll
    for (int k = 0; k < 8; ++k) b3f[k] = *(const s8v*)(bp3g + (k << 9));
    const float bv3 = b3[(g << 7) + gc2];
#pragma unroll
    for (int r = 0; r < 16; ++r) {
      const int rl = (r & 3) + ((r >> 2) << 3) + (lh << 2);
      float v = fmaxf(acc2a[r] + acc2b[r] + bv2, 0.f);
      *(unsigned short*)(H2 + (mt2 << 13) + ((cb2 + (rl << 4)) ^ m2)) = f2bf(v);
    }
    __syncthreads();

    f16v acc3a = zf16(), acc3b = zf16();
#pragma unroll
    for (int i = 0; i < 8; ++i) {
      s8v a3 = *(const s8v*)(H2 + (mt2 << 13) + (((i << 10) + lb) ^ KM(i)));
      if (i & 1) acc3b = mfma32(a3, b3f[i], acc3b);
      else       acc3a = mfma32(a3, b3f[i], acc3a);
#pragma unroll
      for (int jj = 0; jj < 2; ++jj) {
        const int k0 = 16 + (i << 1) + jj;
        s8v a0 = *(const s8v*)(XT + (k0 << 10) + (lane << 4));
        s8v a1 = *(const s8v*)(XT + 32768 + (k0 << 10) + (lane << 4));
        s8v cb = bq1[k0 & 7];
        if (k0 + 8 < 32)
          bq1[k0 & 7] = *(const s8v*)(bp1gn + ((k0 + 8) << 9));
        else if (refill2)
          bq1[k0 & 7] = *(const s8v*)(bp1gnn + ((k0 - 24) << 9));
        accA = mfma32(a0, cb, accA);
        accB = mfma32(a1, cb, accB);
      }
    }
#pragma unroll
    for (int r = 0; r < 16; ++r) {
      const int rl = (r & 3) + ((r >> 2) << 3) + (lh << 2);
      racc[r] += WL[((mt2 << 5) + rl) * 20 + g] * (acc3a[r] + acc3b[r] + bv3);
    }
    {
      const float bv1n = b1[((g + 1) << 8) + gc1];
#pragma unroll
      for (int r = 0; r < 16; ++r) {
        const int rl = (r & 3) + ((r >> 2) << 3) + (lh << 2);
        const int boff = (cb1 + (rl << 4)) ^ m1;
        *(unsigned short*)(H1 + boff) = f2bf(fmaxf(accA[r] + bv1n, 0.f));
        *(unsigned short*)(H1 + 16384 + boff) = f2bf(fmaxf(accB[r] + bv1n, 0.f));
      }
    }
    {
      const unsigned short* const bp2gn = bp2 + ((size_t)(g + 1) << 15);
#pragma unroll
      for (int k = 0; k < 16; ++k) b2f[k] = *(const s8v*)(bp2gn + (k << 9));
      bv2 = b2[((g + 1) << 7) + gc2];
    }
    __syncthreads();
  }

  {
    const int g = NG - 1;
    const unsigned short* const bp3g = bp3 + ((size_t)g << 14);
    f16v acc2a = zf16(), acc2b = zf16();
#pragma unroll
    for (int i = 0; i < 16; ++i) {
      s8v a2 = *(const s8v*)(H1 + (mt2 << 14) + (((i << 10) + lb) ^ KM(i)));
      if (i & 1) acc2b = mfma32(a2, b2f[i], acc2b);
      else       acc2a = mfma32(a2, b2f[i], acc2a);
    }
    s8v b3f[8];
#pragma unroll
    for (int k = 0; k < 8; ++k) b3f[k] = *(const s8v*)(bp3g + (k << 9));
    const float bv3 = b3[(g << 7) + gc2];
#pragma unroll
    for (int r = 0; r < 16; ++r) {
      const int rl = (r & 3) + ((r >> 2) << 3) + (lh << 2);
      float v = fmaxf(acc2a[r] + acc2b[r] + bv2, 0.f);
      *(unsigned short*)(H2 + (mt2 << 13) + ((cb2 + (rl << 4)) ^ m2)) = f2bf(v);
    }
    __syncthreads();

    f16v acc3a = zf16(), acc3b = zf16();
#pragma unroll
    for (int i = 0; i < 8; ++i) {
      s8v a3 = *(const s8v*)(H2 + (mt2 << 13) + (((i << 10) + lb) ^ KM(i)));
      if (i & 1) acc3b = mfma32(a3, b3f[i], acc3b);
      else       acc3a = mfma32(a3, b3f[i], acc3a);
    }
#pragma unroll
    for (int r = 0; r < 16; ++r) {
      const int rl = (r & 3) + ((r >> 2) << 3) + (lh << 2);
      racc[r] += WL[((mt2 << 5) + rl) * 20 + g] * (acc3a[r] + acc3b[r] + bv3);
    }
  }

  s8v bq4[4][2];
#pragma unroll
  for (int k = 0; k < 4; ++k) {
    bq4[k][0] = *(const s8v*)(bp4a + (k << 9));
    bq4[k][1] = *(const s8v*)(bp4b + (k << 9));
  }
  __syncthreads();
#pragma unroll
  for (int r = 0; r < 16; ++r) {
    const int rl = (r & 3) + ((r >> 2) << 3) + (lh << 2);
    *(unsigned short*)(H2 + (mt2 << 13) + ((cb2 + (rl << 4)) ^ m2)) = f2bf(racc[r]);
  }
  __syncthreads();

  f16v acc4[2][2];
  acc4[0][0] = zf16(); acc4[0][1] = zf16();
  acc4[1][0] = zf16(); acc4[1][1] = zf16();
#pragma unroll
  for (int ks = 0; ks < 40; ++ks) {
    s8v bn0, bn1;
    if (ks < 36) {
      bn0 = *(const s8v*)(bp4a + ((ks + 4) << 9));
      bn1 = *(const s8v*)(bp4b + ((ks + 4) << 9));
    }
    s8v a0, a1;
    if (ks < 32) {
      a0 = *(const s8v*)(XT + (ks << 10) + (lane << 4));
      a1 = *(const s8v*)(XT + 32768 + (ks << 10) + (lane << 4));
    } else {
      const int hk = ks - 32;
      a0 = *(const s8v*)(H2 + (((hk << 10) + lb) ^ KM(hk)));
      a1 = *(const s8v*)(H2 + 8192 + (((hk << 10) + lb) ^ KM(hk)));
    }
    acc4[0][0] = mfma32(a0, bq4[ks & 3][0], acc4[0][0]);
    acc4[1][0] = mfma32(a1, bq4[ks & 3][0], acc4[1][0]);
    acc4[0][1] = mfma32(a0, bq4[ks & 3][1], acc4[0][1]);
    acc4[1][1] = mfma32(a1, bq4[ks & 3][1], acc4[1][1]);
    if (ks < 36) { bq4[ks & 3][0] = bn0; bq4[ks & 3][1] = bn1; }
  }
  {
    const float bv4a = bagg[(wid << 5) + l31];
    const float bv4b = bagg[((wid + 8) << 5) + l31];
#pragma unroll
    for (int mt = 0; mt < 2; ++mt)
#pragma unroll
      for (int r = 0; r < 16; ++r) {
        const int rl = (r & 3) + ((r >> 2) << 3) + (lh << 2);
        const size_t rbase = (size_t)(row0 + (mt << 5) + rl) << 9;
        out[rbase + (wid << 5) + l31] = fmaxf(acc4[mt][0][r] + bv4a, 0.f);
        out[rbase + ((wid + 8) << 5) + l31] = fmaxf(acc4[mt][1][r] + bv4b, 0.f);
      }
  }
}

// ---------------- workspace layout (bytes) ----------------
#define OFF_W1P   0u
#define OFF_W2P   4718592u
#define OFF_W3P   5898240u
#define OFF_W4P   6488064u
#define OFF_WAP   7143424u     // dense path only (end 7176192)
// sparse-path extras:
#define OFF_WDN   7176192u     // w dense f32 [16384][18] : 1179648
#define OFF_WAT   8355840u     // wat f32 [18][512]       : 36864
#define OFF_CNT   8392704u     // cnt int[32]             : 128
#define OFF_CCNT  8392832u     // ccnt int[18][64]        : 4608
#define OFF_COFF  8397440u     // coff int[18][64]        : 4608
#define OFF_IDX   8402048u     // idx int[18][8960]       : 645120
#define OFF_WV    9047168u     // wv  f32[18][8960]       : 645120
#define OFF_POS   9692288u     // pos int[16384][18]      : 1179648
#define OFF_H3G   10871936u    // h3g bf16[18][8960][128] : 41287680
#define WS_SPARSE 52159616u

extern "C" void kernel_launch(void* const* d_in, const int* in_sizes, int n_in,
                              void* d_out, int out_size, void* d_ws, size_t ws_size,
                              hipStream_t stream) {
  const float* X    = (const float*)d_in[0];
  const float* GV   = (const float*)d_in[1];
  const float* W1   = (const float*)d_in[2];
  const float* b1   = (const float*)d_in[3];
  const float* W2   = (const float*)d_in[4];
  const float* b2   = (const float*)d_in[5];
  const float* W3   = (const float*)d_in[6];
  const float* b3   = (const float*)d_in[7];
  const float* Wa   = (const float*)d_in[8];
  const float* ba   = (const float*)d_in[9];
  const float* Wagg = (const float*)d_in[10];
  const float* bagg = (const float*)d_in[11];
  float* out = (float*)d_out;
  char* ws = (char*)d_ws;

  unsigned short* w1p = (unsigned short*)(ws + OFF_W1P);
  unsigned short* w2p = (unsigned short*)(ws + OFF_W2P);
  unsigned short* w3p = (unsigned short*)(ws + OFF_W3P);
  unsigned short* w4p = (unsigned short*)(ws + OFF_W4P);

  k_pack<<<dim3(64, 18), 256, 0, stream>>>(W1, w1p, 512, 256);
  k_pack<<<dim3(16, 18), 256, 0, stream>>>(W2, w2p, 256, 128);
  k_pack<<<dim3(8, 18), 256, 0, stream>>>(W3, w3p, 128, 128);
  k_pack<<<dim3(160, 1), 256, 0, stream>>>(Wagg, w4p, 640, 512);

  if (ws_size >= (size_t)WS_SPARSE) {
    float* wdn = (float*)(ws + OFF_WDN);
    float* wat = (float*)(ws + OFF_WAT);
    int* cnt   = (int*)(ws + OFF_CNT);
    int* ccnt  = (int*)(ws + OFF_CCNT);
    int* coff  = (int*)(ws + OFF_COFF);
    int* idx   = (int*)(ws + OFF_IDX);
    float* wvv = (float*)(ws + OFF_WV);
    int* pos   = (int*)(ws + OFF_POS);
    unsigned short* h3g = (unsigned short*)(ws + OFF_H3G);

    k_wat<<<36, 256, 0, stream>>>(Wa, wat);
    k_attn<<<4096, 256, 0, stream>>>(X, GV, wat, ba, wdn);
    k_count<<<64, 256, 0, stream>>>(wdn, ccnt);
    k_scan<<<1, 32, 0, stream>>>(ccnt, coff, cnt);
    k_emit<<<64, 256, 0, stream>>>(wdn, coff, idx, wvv, pos);
    k_expert<<<dim3(140, 18), 512, 0, stream>>>(X, cnt, idx, wvv, w1p, w2p, w3p,
                                                b1, b2, b3, h3g);
    k_agg<<<256, 512, 0, stream>>>(X, pos, h3g, w4p, bagg, out);
  } else {
    unsigned short* wap = (unsigned short*)(ws + OFF_WAP);
    k_packa<<<8, 256, 0, stream>>>(Wa, wap);
    k_main<<<256, 512, 0, stream>>>(X, GV, w1p, w2p, w3p, w4p, wap,
                                    b1, b2, b3, bagg, ba, out);
  }
}

// Round 16
// 163.893 us; speedup vs baseline: 1.3718x; 1.3718x over previous
//
#include <hip/hip_runtime.h>

#define NB 16384
#define ND 512
#define NH 128
#define NHH 256
#define NG 18

typedef short s8v __attribute__((ext_vector_type(8)));
typedef __bf16 bf8v __attribute__((ext_vector_type(8)));
typedef float f16v __attribute__((ext_vector_type(16)));
typedef unsigned int u4v __attribute__((ext_vector_type(4)));

static __device__ __forceinline__ unsigned short f2bf(float f) {
  unsigned int u = __builtin_bit_cast(unsigned int, f);
  u += 0x7FFFu + ((u >> 16) & 1u);
  return (unsigned short)(u >> 16);
}

static __device__ __forceinline__ unsigned pk2(float a, float b) {
  return (unsigned)f2bf(a) | ((unsigned)f2bf(b) << 16);
}

static __device__ __forceinline__ f16v mfma32(s8v a, s8v b, f16v c) {
  return __builtin_amdgcn_mfma_f32_32x32x16_bf16(
      __builtin_bit_cast(bf8v, a), __builtin_bit_cast(bf8v, b), c, 0, 0, 0);
}

static __device__ __forceinline__ f16v zf16() {
  f16v v;
#pragma unroll
  for (int i = 0; i < 16; ++i) v[i] = 0.f;
  return v;
}

// per-ks compile-time swizzle XOR for fragment-linear H1/H2 reads
#define KM(ks) (((((ks) & 1) << 5)) | ((((ks) >> 1) & 1) << 6))

// pack W [G][K][N] f32 -> B-fragment-linear bf16 for mfma_32x32x16
__global__ __launch_bounds__(256) void k_pack(const float* __restrict__ in,
                                              unsigned short* __restrict__ out,
                                              int K, int N) {
  const int g = blockIdx.y;
  const int c = blockIdx.x * 256 + threadIdx.x;
  const int nk = K >> 4;
  const int l = c & 63;
  const int t = c >> 6;
  const int nt = t / nk;
  const int ks = t - nt * nk;
  const int k0 = (ks << 4) + ((l >> 5) << 3);
  const int col = (nt << 5) + (l & 31);
  const float* ip = in + (size_t)g * K * N + (size_t)k0 * N + col;
  u4v pk;
#pragma unroll
  for (int j = 0; j < 4; ++j)
    pk[j] = pk2(ip[(size_t)(2 * j) * N], ip[(size_t)(2 * j + 1) * N]);
  *(u4v*)(out + (size_t)g * K * N + ((size_t)c << 3)) = pk;
}

// pack Wa [512][18] -> fragment stream [32 ks][64 lane][8], cols >= 18 zeroed
__global__ __launch_bounds__(256) void k_packa(const float* __restrict__ wa,
                                               unsigned short* __restrict__ wap) {
  const int t = blockIdx.x * 256 + threadIdx.x;  // 0..2047
  const int ks = t >> 6, l = t & 63;
  const int col = l & 31;
  const int k0 = (ks << 4) + ((l >> 5) << 3);
  u4v pk;
  if (col < 18) {
    const float* ip = wa + (size_t)k0 * NG + col;
#pragma unroll
    for (int j = 0; j < 4; ++j)
      pk[j] = pk2(ip[(size_t)(2 * j) * NG], ip[(size_t)(2 * j + 1) * NG]);
  } else {
    pk[0] = pk[1] = pk[2] = pk[3] = 0u;
  }
  *(u4v*)(wap + ((size_t)t << 3)) = pk;
}

// fused attn + experts + aggregation. 1 block = 64 rows, 8 waves, mfma 32x32x16.
// R14 structure + s_setprio(1) around MFMA-dense bodies (T5 A/B).
__global__ __launch_bounds__(512, 1) void k_main(
    const float* __restrict__ X,              // [B][512] f32
    const float* __restrict__ GV,             // [B][18]
    const unsigned short* __restrict__ w1p,   // packed [18][512x256]
    const unsigned short* __restrict__ w2p,   // packed [18][256x128]
    const unsigned short* __restrict__ w3p,   // packed [18][128x128]
    const unsigned short* __restrict__ w4p,   // packed [640x512]
    const unsigned short* __restrict__ wap,   // packed Wa [512x32]
    const float* __restrict__ b1, const float* __restrict__ b2,
    const float* __restrict__ b3, const float* __restrict__ bagg,
    const float* __restrict__ ba,
    float* __restrict__ out) {
  __shared__ __align__(16) char smem[128256];
  char* const XT = smem;                      // [2][32][1024] = 64KB (linear)
  char* const H1 = smem + 65536;              // [2][16][1024] = 32KB (swz)
  char* const H2 = smem + 98304;              // [2][8][1024]  = 16KB (swz)
  float* const WL = (float*)(smem + 114688);  // [64][20] f32
  float* const Lsm = (float*)(smem + 119808); // [64][33] f32

  const int tid = threadIdx.x;
  const int row0 = blockIdx.x << 6;
  const int wid = tid >> 6, lane = tid & 63;
  const int l31 = lane & 31, lh = lane >> 5;
  const int lb = (lane << 4) ^ (lh << 4);     // swizzled read lane-base

  // ---- stage XT (f32 -> bf16) in fragment-linear order
#pragma unroll
  for (int i = 0; i < 8; ++i) {
    int ck = (i << 9) + tid;                  // chunk 0..4095
    int mt = ck >> 11, ks = (ck >> 6) & 31, l = ck & 63;
    int grow = row0 + (mt << 5) + (l & 31);
    int c8 = (ks << 1) + (l >> 5);
    const float* xp = X + ((size_t)grow << 9) + (c8 << 3);
    float4 xa = *(const float4*)xp;
    float4 xc = *(const float4*)(xp + 4);
    u4v p;
    p[0] = pk2(xa.x, xa.y); p[1] = pk2(xa.z, xa.w);
    p[2] = pk2(xc.x, xc.y); p[3] = pk2(xc.z, xc.w);
    *(u4v*)(XT + (ck << 4)) = p;
  }

  // GEMM1 per-wave B base (col-tile = wid); depth-8 queue, g=0 ks0..7
  const unsigned short* const bp1 = w1p + (wid << 14) + (lane << 3);
  s8v bq1[8];
#pragma unroll
  for (int i = 0; i < 8; ++i) bq1[i] = *(const s8v*)(bp1 + (i << 9));

  __syncthreads();

  // ---- attention logits: L = X @ Wa + ba via MFMA (waves 0,1)
  if (wid < 2) {
    f16v accL = zf16();
    const unsigned short* const bpa = wap + (lane << 3);
#pragma unroll
    for (int ks = 0; ks < 32; ++ks) {
      s8v a = *(const s8v*)(XT + (wid << 15) + (ks << 10) + (lane << 4));
      s8v b = *(const s8v*)(bpa + (ks << 9));
      accL = mfma32(a, b, accL);
    }
    const float bav = (l31 < NG) ? ba[l31] : 0.f;
#pragma unroll
    for (int r = 0; r < 16; ++r) {
      const int rl = (r & 3) + ((r >> 2) << 3) + (lh << 2);
      Lsm[((wid << 5) + rl) * 33 + l31] = accL[r] + bav;
    }
  }
  __syncthreads();

  // ---- softmax * genre mask -> WL (8 lanes per wave, one row each)
  if (lane < 8) {
    const int row = (wid << 3) + lane;
    float lg[NG], mx = -3.4e38f;
#pragma unroll
    for (int q = 0; q < NG; ++q) { lg[q] = Lsm[row * 33 + q]; mx = fmaxf(mx, lg[q]); }
    float s = 0.f;
#pragma unroll
    for (int q = 0; q < NG; ++q) { lg[q] = expf(lg[q] - mx); s += lg[q]; }
    const float inv = 1.f / s;
#pragma unroll
    for (int q = 0; q < NG; ++q) {
      float gv = GV[(size_t)(row0 + row) * NG + q];
      WL[row * 20 + q] = gv > 0.f ? lg[q] * inv * gv : 0.f;
    }
  }

  // ---- wave tile assignment
  const int nt2 = wid & 3, mt2 = wid >> 2;    // GEMM2/3 tile
  const unsigned short* const bp2 = w2p + (nt2 << 13) + (lane << 3);
  const unsigned short* const bp3 = w3p + (nt2 << 12) + (lane << 3);
  const unsigned short* const bp4a = w4p + (size_t)wid * 20480 + (lane << 3);
  const unsigned short* const bp4b = w4p + (size_t)(wid + 8) * 20480 + (lane << 3);

  // per-lane swizzled write bases (genre-invariant)
  const int gc1 = (wid << 5) + l31;           // GEMM1 col
  const int gc2 = (nt2 << 5) + l31;           // GEMM2/3 col
  const int cb1 = ((gc1 >> 4) << 10) + (((gc1 >> 3) & 1) << 9) + ((gc1 & 7) << 1);
  const int cb2 = ((gc2 >> 4) << 10) + (((gc2 >> 3) & 1) << 9) + ((gc2 & 7) << 1);
  const int m1 = (((cb1 >> 9) & 1) << 4) | (((cb1 >> 10) & 1) << 5) | (((cb1 >> 11) & 1) << 6);
  const int m2 = (((cb2 >> 9) & 1) << 4) | (((cb2 >> 10) & 1) << 5) | (((cb2 >> 11) & 1) << 6);

  f16v racc = zf16();
  s8v b2f[16];
  float bv2;

  // ---- prologue: GEMM1(0) full (not pipelined), depth-8 queue
  {
    f16v accA0 = zf16(), accA1 = zf16(), accB0 = zf16(), accB1 = zf16();
    __builtin_amdgcn_s_setprio(1);
#pragma unroll
    for (int ks = 0; ks < 32; ++ks) {
      s8v bn;
      {
        size_t off = (ks < 24) ? (size_t)((ks + 8) << 9)
                               : (size_t)131072 + ((ks - 24) << 9);  // g=1 frags 0..7
        bn = *(const s8v*)(bp1 + off);
      }
      s8v a0 = *(const s8v*)(XT + (ks << 10) + (lane << 4));
      s8v a1 = *(const s8v*)(XT + 32768 + (ks << 10) + (lane << 4));
      if (ks & 1) {
        accA1 = mfma32(a0, bq1[ks & 7], accA1);
        accB1 = mfma32(a1, bq1[ks & 7], accB1);
      } else {
        accA0 = mfma32(a0, bq1[ks & 7], accA0);
        accB0 = mfma32(a1, bq1[ks & 7], accB0);
      }
      bq1[ks & 7] = bn;
    }
    __builtin_amdgcn_s_setprio(0);
    const float bv1 = b1[gc1];
#pragma unroll
    for (int r = 0; r < 16; ++r) {
      const int rl = (r & 3) + ((r >> 2) << 3) + (lh << 2);
      const int boff = (cb1 + (rl << 4)) ^ m1;
      *(unsigned short*)(H1 + boff) = f2bf(fmaxf(accA0[r] + accA1[r] + bv1, 0.f));
      *(unsigned short*)(H1 + 16384 + boff) = f2bf(fmaxf(accB0[r] + accB1[r] + bv1, 0.f));
    }
    // b2f full preload (W2 g=0) + bias — completes inside the barrier drain
#pragma unroll
    for (int k = 0; k < 16; ++k) b2f[k] = *(const s8v*)(bp2 + (k << 9));
    bv2 = b2[gc2];
  }
  __syncthreads();   // H1(0) + WL visible; b2f ready

  // ---- main pipelined loop: iteration g does GEMM2/3(g) + GEMM1(g+1)
  for (int g = 0; g < NG - 1; ++g) {
    const unsigned short* const bp1gn = bp1 + (size_t)(g + 1) * 131072;
    const unsigned short* const bp1gnn = bp1 + (size_t)(g + 2) * 131072;
    const unsigned short* const bp3g = bp3 + ((size_t)g << 14);
    const bool refill2 = (g + 2 < NG);

    // -------- Phase A: GEMM2(g) + GEMM1(g+1) ks0..15 --------
    f16v acc2a = zf16(), acc2b = zf16();
    f16v accA = zf16(), accB = zf16();
    __builtin_amdgcn_s_setprio(1);
#pragma unroll
    for (int i = 0; i < 16; ++i) {
      s8v a2 = *(const s8v*)(H1 + (mt2 << 14) + (((i << 10) + lb) ^ KM(i)));
      s8v a0 = *(const s8v*)(XT + (i << 10) + (lane << 4));
      s8v a1 = *(const s8v*)(XT + 32768 + (i << 10) + (lane << 4));
      s8v cb = bq1[i & 7];
      bq1[i & 7] = *(const s8v*)(bp1gn + ((i + 8) << 9));
      if (i & 1) acc2b = mfma32(a2, b2f[i], acc2b);
      else       acc2a = mfma32(a2, b2f[i], acc2a);
      accA = mfma32(a0, cb, accA);
      accB = mfma32(a1, cb, accB);
    }
    __builtin_amdgcn_s_setprio(0);
    // b3f preload + H2(g) write (loads complete inside the barrier drain)
    s8v b3f[8];
#pragma unroll
    for (int k = 0; k < 8; ++k) b3f[k] = *(const s8v*)(bp3g + (k << 9));
    const float bv3 = b3[(g << 7) + gc2];
#pragma unroll
    for (int r = 0; r < 16; ++r) {
      const int rl = (r & 3) + ((r >> 2) << 3) + (lh << 2);
      float v = fmaxf(acc2a[r] + acc2b[r] + bv2, 0.f);
      *(unsigned short*)(H2 + (mt2 << 13) + ((cb2 + (rl << 4)) ^ m2)) = f2bf(v);
    }
    __syncthreads();

    // -------- Phase B: GEMM3(g) + GEMM1(g+1) ks16..31 --------
    f16v acc3a = zf16(), acc3b = zf16();
    __builtin_amdgcn_s_setprio(1);
#pragma unroll
    for (int i = 0; i < 8; ++i) {
      s8v a3 = *(const s8v*)(H2 + (mt2 << 13) + (((i << 10) + lb) ^ KM(i)));
      if (i & 1) acc3b = mfma32(a3, b3f[i], acc3b);
      else       acc3a = mfma32(a3, b3f[i], acc3a);
#pragma unroll
      for (int jj = 0; jj < 2; ++jj) {
        const int k0 = 16 + (i << 1) + jj;
        s8v a0 = *(const s8v*)(XT + (k0 << 10) + (lane << 4));
        s8v a1 = *(const s8v*)(XT + 32768 + (k0 << 10) + (lane << 4));
        s8v cb = bq1[k0 & 7];
        if (k0 + 8 < 32)
          bq1[k0 & 7] = *(const s8v*)(bp1gn + ((k0 + 8) << 9));
        else if (refill2)
          bq1[k0 & 7] = *(const s8v*)(bp1gnn + ((k0 - 24) << 9));
        accA = mfma32(a0, cb, accA);
        accB = mfma32(a1, cb, accB);
      }
    }
    __builtin_amdgcn_s_setprio(0);
#pragma unroll
    for (int r = 0; r < 16; ++r) {
      const int rl = (r & 3) + ((r >> 2) << 3) + (lh << 2);
      racc[r] += WL[((mt2 << 5) + rl) * 20 + g] * (acc3a[r] + acc3b[r] + bv3);
    }
    // H1(g+1) write
    {
      const float bv1n = b1[((g + 1) << 8) + gc1];
#pragma unroll
      for (int r = 0; r < 16; ++r) {
        const int rl = (r & 3) + ((r >> 2) << 3) + (lh << 2);
        const int boff = (cb1 + (rl << 4)) ^ m1;
        *(unsigned short*)(H1 + boff) = f2bf(fmaxf(accA[r] + bv1n, 0.f));
        *(unsigned short*)(H1 + 16384 + boff) = f2bf(fmaxf(accB[r] + bv1n, 0.f));
      }
    }
    // b2f full preload for genre g+1 + bias (free under the barrier drain)
    {
      const unsigned short* const bp2gn = bp2 + ((size_t)(g + 1) << 15);
#pragma unroll
      for (int k = 0; k < 16; ++k) b2f[k] = *(const s8v*)(bp2gn + (k << 9));
      bv2 = b2[((g + 1) << 7) + gc2];
    }
    __syncthreads();
  }

  // ---- tail: GEMM2/3 for last genre (no GEMM1 to pipeline)
  {
    const int g = NG - 1;
    const unsigned short* const bp3g = bp3 + ((size_t)g << 14);
    f16v acc2a = zf16(), acc2b = zf16();
    __builtin_amdgcn_s_setprio(1);
#pragma unroll
    for (int i = 0; i < 16; ++i) {
      s8v a2 = *(const s8v*)(H1 + (mt2 << 14) + (((i << 10) + lb) ^ KM(i)));
      if (i & 1) acc2b = mfma32(a2, b2f[i], acc2b);
      else       acc2a = mfma32(a2, b2f[i], acc2a);
    }
    __builtin_amdgcn_s_setprio(0);
    s8v b3f[8];
#pragma unroll
    for (int k = 0; k < 8; ++k) b3f[k] = *(const s8v*)(bp3g + (k << 9));
    const float bv3 = b3[(g << 7) + gc2];
#pragma unroll
    for (int r = 0; r < 16; ++r) {
      const int rl = (r & 3) + ((r >> 2) << 3) + (lh << 2);
      float v = fmaxf(acc2a[r] + acc2b[r] + bv2, 0.f);
      *(unsigned short*)(H2 + (mt2 << 13) + ((cb2 + (rl << 4)) ^ m2)) = f2bf(v);
    }
    __syncthreads();

    f16v acc3a = zf16(), acc3b = zf16();
#pragma unroll
    for (int i = 0; i < 8; ++i) {
      s8v a3 = *(const s8v*)(H2 + (mt2 << 13) + (((i << 10) + lb) ^ KM(i)));
      if (i & 1) acc3b = mfma32(a3, b3f[i], acc3b);
      else       acc3a = mfma32(a3, b3f[i], acc3a);
    }
#pragma unroll
    for (int r = 0; r < 16; ++r) {
      const int rl = (r & 3) + ((r >> 2) << 3) + (lh << 2);
      racc[r] += WL[((mt2 << 5) + rl) * 20 + g] * (acc3a[r] + acc3b[r] + bv3);
    }
  }

  // prefetch GEMM4 depth-4 dual queue (flies across the barriers)
  s8v bq4[4][2];
#pragma unroll
  for (int k = 0; k < 4; ++k) {
    bq4[k][0] = *(const s8v*)(bp4a + (k << 9));
    bq4[k][1] = *(const s8v*)(bp4b + (k << 9));
  }
  __syncthreads();  // all GEMM3 H2 reads done
#pragma unroll
  for (int r = 0; r < 16; ++r) {
    const int rl = (r & 3) + ((r >> 2) << 3) + (lh << 2);
    *(unsigned short*)(H2 + (mt2 << 13) + ((cb2 + (rl << 4)) ^ m2)) = f2bf(racc[r]);
  }
  __syncthreads();

  // ---------- GEMM4: out = relu([X | ref] @ Wagg + bagg)  [64,512] ----------
  f16v acc4[2][2];
  acc4[0][0] = zf16(); acc4[0][1] = zf16();
  acc4[1][0] = zf16(); acc4[1][1] = zf16();
  __builtin_amdgcn_s_setprio(1);
#pragma unroll
  for (int ks = 0; ks < 40; ++ks) {
    s8v bn0, bn1;
    if (ks < 36) {
      bn0 = *(const s8v*)(bp4a + ((ks + 4) << 9));
      bn1 = *(const s8v*)(bp4b + ((ks + 4) << 9));
    }
    s8v a0, a1;
    if (ks < 32) {
      a0 = *(const s8v*)(XT + (ks << 10) + (lane << 4));
      a1 = *(const s8v*)(XT + 32768 + (ks << 10) + (lane << 4));
    } else {
      const int hk = ks - 32;
      a0 = *(const s8v*)(H2 + (((hk << 10) + lb) ^ KM(hk)));
      a1 = *(const s8v*)(H2 + 8192 + (((hk << 10) + lb) ^ KM(hk)));
    }
    acc4[0][0] = mfma32(a0, bq4[ks & 3][0], acc4[0][0]);
    acc4[1][0] = mfma32(a1, bq4[ks & 3][0], acc4[1][0]);
    acc4[0][1] = mfma32(a0, bq4[ks & 3][1], acc4[0][1]);
    acc4[1][1] = mfma32(a1, bq4[ks & 3][1], acc4[1][1]);
    if (ks < 36) { bq4[ks & 3][0] = bn0; bq4[ks & 3][1] = bn1; }
  }
  __builtin_amdgcn_s_setprio(0);
  {
    const float bv4a = bagg[(wid << 5) + l31];
    const float bv4b = bagg[((wid + 8) << 5) + l31];
#pragma unroll
    for (int mt = 0; mt < 2; ++mt)
#pragma unroll
      for (int r = 0; r < 16; ++r) {
        const int rl = (r & 3) + ((r >> 2) << 3) + (lh << 2);
        const size_t rbase = (size_t)(row0 + (mt << 5) + rl) << 9;
        out[rbase + (wid << 5) + l31] = fmaxf(acc4[mt][0][r] + bv4a, 0.f);
        out[rbase + ((wid + 8) << 5) + l31] = fmaxf(acc4[mt][1][r] + bv4b, 0.f);
      }
  }
}

// ---------------- workspace layout (bytes) ----------------
#define OFF_W1P   0u          // packed W1   : 4718592
#define OFF_W2P   4718592u    // packed W2   : 1179648
#define OFF_W3P   5898240u    // packed W3   : 589824
#define OFF_W4P   6488064u    // packed Wagg : 655360
#define OFF_WAP   7143424u    // packed Wa   : 32768   (end 7176192)

extern "C" void kernel_launch(void* const* d_in, const int* in_sizes, int n_in,
                              void* d_out, int out_size, void* d_ws, size_t ws_size,
                              hipStream_t stream) {
  const float* X    = (const float*)d_in[0];
  const float* GV   = (const float*)d_in[1];
  const float* W1   = (const float*)d_in[2];
  const float* b1   = (const float*)d_in[3];
  const float* W2   = (const float*)d_in[4];
  const float* b2   = (const float*)d_in[5];
  const float* W3   = (const float*)d_in[6];
  const float* b3   = (const float*)d_in[7];
  const float* Wa   = (const float*)d_in[8];
  const float* ba   = (const float*)d_in[9];
  const float* Wagg = (const float*)d_in[10];
  const float* bagg = (const float*)d_in[11];
  float* out = (float*)d_out;
  char* ws = (char*)d_ws;

  unsigned short* w1p = (unsigned short*)(ws + OFF_W1P);
  unsigned short* w2p = (unsigned short*)(ws + OFF_W2P);
  unsigned short* w3p = (unsigned short*)(ws + OFF_W3P);
  unsigned short* w4p = (unsigned short*)(ws + OFF_W4P);
  unsigned short* wap = (unsigned short*)(ws + OFF_WAP);

  k_pack<<<dim3(64, 18), 256, 0, stream>>>(W1, w1p, 512, 256);
  k_pack<<<dim3(16, 18), 256, 0, stream>>>(W2, w2p, 256, 128);
  k_pack<<<dim3(8, 18), 256, 0, stream>>>(W3, w3p, 128, 128);
  k_pack<<<dim3(160, 1), 256, 0, stream>>>(Wagg, w4p, 640, 512);
  k_packa<<<8, 256, 0, stream>>>(Wa, wap);
  k_main<<<256, 512, 0, stream>>>(X, GV, w1p, w2p, w3p, w4p, wap,
                                  b1, b2, b3, bagg, ba, out);
}

// Round 17
// 159.651 us; speedup vs baseline: 1.4083x; 1.0266x over previous
//
#include <hip/hip_runtime.h>

#define NB 16384
#define ND 512
#define NH 128
#define NHH 256
#define NG 18

typedef short s8v __attribute__((ext_vector_type(8)));
typedef __bf16 bf8v __attribute__((ext_vector_type(8)));
typedef float f16v __attribute__((ext_vector_type(16)));
typedef unsigned int u4v __attribute__((ext_vector_type(4)));

static __device__ __forceinline__ unsigned short f2bf(float f) {
  unsigned int u = __builtin_bit_cast(unsigned int, f);
  u += 0x7FFFu + ((u >> 16) & 1u);
  return (unsigned short)(u >> 16);
}

static __device__ __forceinline__ unsigned pk2(float a, float b) {
  return (unsigned)f2bf(a) | ((unsigned)f2bf(b) << 16);
}

static __device__ __forceinline__ f16v mfma32(s8v a, s8v b, f16v c) {
  return __builtin_amdgcn_mfma_f32_32x32x16_bf16(
      __builtin_bit_cast(bf8v, a), __builtin_bit_cast(bf8v, b), c, 0, 0, 0);
}

static __device__ __forceinline__ f16v zf16() {
  f16v v;
#pragma unroll
  for (int i = 0; i < 16; ++i) v[i] = 0.f;
  return v;
}

// per-ks compile-time swizzle XOR for fragment-linear H1/H2 reads
#define KM(ks) (((((ks) & 1) << 5)) | ((((ks) >> 1) & 1) << 6))

// pack W [G][K][N] f32 -> B-fragment-linear bf16 for mfma_32x32x16
__global__ __launch_bounds__(256) void k_pack(const float* __restrict__ in,
                                              unsigned short* __restrict__ out,
                                              int K, int N) {
  const int g = blockIdx.y;
  const int c = blockIdx.x * 256 + threadIdx.x;
  const int nk = K >> 4;
  const int l = c & 63;
  const int t = c >> 6;
  const int nt = t / nk;
  const int ks = t - nt * nk;
  const int k0 = (ks << 4) + ((l >> 5) << 3);
  const int col = (nt << 5) + (l & 31);
  const float* ip = in + (size_t)g * K * N + (size_t)k0 * N + col;
  u4v pk;
#pragma unroll
  for (int j = 0; j < 4; ++j)
    pk[j] = pk2(ip[(size_t)(2 * j) * N], ip[(size_t)(2 * j + 1) * N]);
  *(u4v*)(out + (size_t)g * K * N + ((size_t)c << 3)) = pk;
}

// pack Wa [512][18] -> fragment stream [32 ks][64 lane][8], cols >= 18 zeroed
__global__ __launch_bounds__(256) void k_packa(const float* __restrict__ wa,
                                               unsigned short* __restrict__ wap) {
  const int t = blockIdx.x * 256 + threadIdx.x;  // 0..2047
  const int ks = t >> 6, l = t & 63;
  const int col = l & 31;
  const int k0 = (ks << 4) + ((l >> 5) << 3);
  u4v pk;
  if (col < 18) {
    const float* ip = wa + (size_t)k0 * NG + col;
#pragma unroll
    for (int j = 0; j < 4; ++j)
      pk[j] = pk2(ip[(size_t)(2 * j) * NG], ip[(size_t)(2 * j + 1) * NG]);
  } else {
    pk[0] = pk[1] = pk[2] = pk[3] = 0u;
  }
  *(u4v*)(wap + ((size_t)t << 3)) = pk;
}

// fused attn + experts + aggregation. 1 block = 64 rows, 8 waves, mfma 32x32x16.
// Cross-genre pipeline + "loads pre-barrier are free" discipline:
//   b2f[16]/b3f[8] fully hoisted before their barriers; GEMM1 queue depth 8.
__global__ __launch_bounds__(512, 1) void k_main(
    const float* __restrict__ X,              // [B][512] f32
    const float* __restrict__ GV,             // [B][18]
    const unsigned short* __restrict__ w1p,   // packed [18][512x256]
    const unsigned short* __restrict__ w2p,   // packed [18][256x128]
    const unsigned short* __restrict__ w3p,   // packed [18][128x128]
    const unsigned short* __restrict__ w4p,   // packed [640x512]
    const unsigned short* __restrict__ wap,   // packed Wa [512x32]
    const float* __restrict__ b1, const float* __restrict__ b2,
    const float* __restrict__ b3, const float* __restrict__ bagg,
    const float* __restrict__ ba,
    float* __restrict__ out) {
  __shared__ __align__(16) char smem[128256];
  char* const XT = smem;                      // [2][32][1024] = 64KB (linear)
  char* const H1 = smem + 65536;              // [2][16][1024] = 32KB (swz)
  char* const H2 = smem + 98304;              // [2][8][1024]  = 16KB (swz)
  float* const WL = (float*)(smem + 114688);  // [64][20] f32
  float* const Lsm = (float*)(smem + 119808); // [64][33] f32

  const int tid = threadIdx.x;
  const int row0 = blockIdx.x << 6;
  const int wid = tid >> 6, lane = tid & 63;
  const int l31 = lane & 31, lh = lane >> 5;
  const int lb = (lane << 4) ^ (lh << 4);     // swizzled read lane-base

  // ---- stage XT (f32 -> bf16) in fragment-linear order
#pragma unroll
  for (int i = 0; i < 8; ++i) {
    int ck = (i << 9) + tid;                  // chunk 0..4095
    int mt = ck >> 11, ks = (ck >> 6) & 31, l = ck & 63;
    int grow = row0 + (mt << 5) + (l & 31);
    int c8 = (ks << 1) + (l >> 5);
    const float* xp = X + ((size_t)grow << 9) + (c8 << 3);
    float4 xa = *(const float4*)xp;
    float4 xc = *(const float4*)(xp + 4);
    u4v p;
    p[0] = pk2(xa.x, xa.y); p[1] = pk2(xa.z, xa.w);
    p[2] = pk2(xc.x, xc.y); p[3] = pk2(xc.z, xc.w);
    *(u4v*)(XT + (ck << 4)) = p;
  }

  // GEMM1 per-wave B base (col-tile = wid); depth-8 queue, g=0 ks0..7
  const unsigned short* const bp1 = w1p + (wid << 14) + (lane << 3);
  s8v bq1[8];
#pragma unroll
  for (int i = 0; i < 8; ++i) bq1[i] = *(const s8v*)(bp1 + (i << 9));

  __syncthreads();

  // ---- attention logits: L = X @ Wa + ba via MFMA (waves 0,1)
  if (wid < 2) {
    f16v accL = zf16();
    const unsigned short* const bpa = wap + (lane << 3);
#pragma unroll
    for (int ks = 0; ks < 32; ++ks) {
      s8v a = *(const s8v*)(XT + (wid << 15) + (ks << 10) + (lane << 4));
      s8v b = *(const s8v*)(bpa + (ks << 9));
      accL = mfma32(a, b, accL);
    }
    const float bav = (l31 < NG) ? ba[l31] : 0.f;
#pragma unroll
    for (int r = 0; r < 16; ++r) {
      const int rl = (r & 3) + ((r >> 2) << 3) + (lh << 2);
      Lsm[((wid << 5) + rl) * 33 + l31] = accL[r] + bav;
    }
  }
  __syncthreads();

  // ---- softmax * genre mask -> WL (8 lanes per wave, one row each)
  if (lane < 8) {
    const int row = (wid << 3) + lane;
    float lg[NG], mx = -3.4e38f;
#pragma unroll
    for (int q = 0; q < NG; ++q) { lg[q] = Lsm[row * 33 + q]; mx = fmaxf(mx, lg[q]); }
    float s = 0.f;
#pragma unroll
    for (int q = 0; q < NG; ++q) { lg[q] = expf(lg[q] - mx); s += lg[q]; }
    const float inv = 1.f / s;
#pragma unroll
    for (int q = 0; q < NG; ++q) {
      float gv = GV[(size_t)(row0 + row) * NG + q];
      WL[row * 20 + q] = gv > 0.f ? lg[q] * inv * gv : 0.f;
    }
  }

  // ---- wave tile assignment
  const int nt2 = wid & 3, mt2 = wid >> 2;    // GEMM2/3 tile
  const unsigned short* const bp2 = w2p + (nt2 << 13) + (lane << 3);
  const unsigned short* const bp3 = w3p + (nt2 << 12) + (lane << 3);
  const unsigned short* const bp4a = w4p + (size_t)wid * 20480 + (lane << 3);
  const unsigned short* const bp4b = w4p + (size_t)(wid + 8) * 20480 + (lane << 3);

  // per-lane swizzled write bases (genre-invariant)
  const int gc1 = (wid << 5) + l31;           // GEMM1 col
  const int gc2 = (nt2 << 5) + l31;           // GEMM2/3 col
  const int cb1 = ((gc1 >> 4) << 10) + (((gc1 >> 3) & 1) << 9) + ((gc1 & 7) << 1);
  const int cb2 = ((gc2 >> 4) << 10) + (((gc2 >> 3) & 1) << 9) + ((gc2 & 7) << 1);
  const int m1 = (((cb1 >> 9) & 1) << 4) | (((cb1 >> 10) & 1) << 5) | (((cb1 >> 11) & 1) << 6);
  const int m2 = (((cb2 >> 9) & 1) << 4) | (((cb2 >> 10) & 1) << 5) | (((cb2 >> 11) & 1) << 6);

  f16v racc = zf16();
  s8v b2f[16];
  float bv2;

  // ---- prologue: GEMM1(0) full (not pipelined), depth-8 queue
  {
    f16v accA0 = zf16(), accA1 = zf16(), accB0 = zf16(), accB1 = zf16();
#pragma unroll
    for (int ks = 0; ks < 32; ++ks) {
      s8v bn;
      {
        size_t off = (ks < 24) ? (size_t)((ks + 8) << 9)
                               : (size_t)131072 + ((ks - 24) << 9);  // g=1 frags 0..7
        bn = *(const s8v*)(bp1 + off);
      }
      s8v a0 = *(const s8v*)(XT + (ks << 10) + (lane << 4));
      s8v a1 = *(const s8v*)(XT + 32768 + (ks << 10) + (lane << 4));
      if (ks & 1) {
        accA1 = mfma32(a0, bq1[ks & 7], accA1);
        accB1 = mfma32(a1, bq1[ks & 7], accB1);
      } else {
        accA0 = mfma32(a0, bq1[ks & 7], accA0);
        accB0 = mfma32(a1, bq1[ks & 7], accB0);
      }
      bq1[ks & 7] = bn;
    }
    const float bv1 = b1[gc1];
#pragma unroll
    for (int r = 0; r < 16; ++r) {
      const int rl = (r & 3) + ((r >> 2) << 3) + (lh << 2);
      const int boff = (cb1 + (rl << 4)) ^ m1;
      *(unsigned short*)(H1 + boff) = f2bf(fmaxf(accA0[r] + accA1[r] + bv1, 0.f));
      *(unsigned short*)(H1 + 16384 + boff) = f2bf(fmaxf(accB0[r] + accB1[r] + bv1, 0.f));
    }
    // b2f full preload (W2 g=0) + bias — completes inside the barrier drain
#pragma unroll
    for (int k = 0; k < 16; ++k) b2f[k] = *(const s8v*)(bp2 + (k << 9));
    bv2 = b2[gc2];
  }
  __syncthreads();   // H1(0) + WL visible; b2f ready

  // ---- main pipelined loop: iteration g does GEMM2/3(g) + GEMM1(g+1)
  for (int g = 0; g < NG - 1; ++g) {
    const unsigned short* const bp1gn = bp1 + (size_t)(g + 1) * 131072;
    const unsigned short* const bp1gnn = bp1 + (size_t)(g + 2) * 131072;
    const unsigned short* const bp3g = bp3 + ((size_t)g << 14);
    const bool refill2 = (g + 2 < NG);

    // -------- Phase A: GEMM2(g) + GEMM1(g+1) ks0..15 --------
    f16v acc2a = zf16(), acc2b = zf16();
    f16v accA = zf16(), accB = zf16();
#pragma unroll
    for (int i = 0; i < 16; ++i) {
      s8v a2 = *(const s8v*)(H1 + (mt2 << 14) + (((i << 10) + lb) ^ KM(i)));
      s8v a0 = *(const s8v*)(XT + (i << 10) + (lane << 4));
      s8v a1 = *(const s8v*)(XT + 32768 + (i << 10) + (lane << 4));
      s8v cb = bq1[i & 7];
      bq1[i & 7] = *(const s8v*)(bp1gn + ((i + 8) << 9));
      if (i & 1) acc2b = mfma32(a2, b2f[i], acc2b);
      else       acc2a = mfma32(a2, b2f[i], acc2a);
      accA = mfma32(a0, cb, accA);
      accB = mfma32(a1, cb, accB);
    }
    // b3f preload + H2(g) write (loads complete inside the barrier drain)
    s8v b3f[8];
#pragma unroll
    for (int k = 0; k < 8; ++k) b3f[k] = *(const s8v*)(bp3g + (k << 9));
    const float bv3 = b3[(g << 7) + gc2];
#pragma unroll
    for (int r = 0; r < 16; ++r) {
      const int rl = (r & 3) + ((r >> 2) << 3) + (lh << 2);
      float v = fmaxf(acc2a[r] + acc2b[r] + bv2, 0.f);
      *(unsigned short*)(H2 + (mt2 << 13) + ((cb2 + (rl << 4)) ^ m2)) = f2bf(v);
    }
    __syncthreads();

    // -------- Phase B: GEMM3(g) + GEMM1(g+1) ks16..31 --------
    f16v acc3a = zf16(), acc3b = zf16();
#pragma unroll
    for (int i = 0; i < 8; ++i) {
      s8v a3 = *(const s8v*)(H2 + (mt2 << 13) + (((i << 10) + lb) ^ KM(i)));
      if (i & 1) acc3b = mfma32(a3, b3f[i], acc3b);
      else       acc3a = mfma32(a3, b3f[i], acc3a);
#pragma unroll
      for (int jj = 0; jj < 2; ++jj) {
        const int k0 = 16 + (i << 1) + jj;
        s8v a0 = *(const s8v*)(XT + (k0 << 10) + (lane << 4));
        s8v a1 = *(const s8v*)(XT + 32768 + (k0 << 10) + (lane << 4));
        s8v cb = bq1[k0 & 7];
        if (k0 + 8 < 32)
          bq1[k0 & 7] = *(const s8v*)(bp1gn + ((k0 + 8) << 9));
        else if (refill2)
          bq1[k0 & 7] = *(const s8v*)(bp1gnn + ((k0 - 24) << 9));
        accA = mfma32(a0, cb, accA);
        accB = mfma32(a1, cb, accB);
      }
    }
#pragma unroll
    for (int r = 0; r < 16; ++r) {
      const int rl = (r & 3) + ((r >> 2) << 3) + (lh << 2);
      racc[r] += WL[((mt2 << 5) + rl) * 20 + g] * (acc3a[r] + acc3b[r] + bv3);
    }
    // H1(g+1) write
    {
      const float bv1n = b1[((g + 1) << 8) + gc1];
#pragma unroll
      for (int r = 0; r < 16; ++r) {
        const int rl = (r & 3) + ((r >> 2) << 3) + (lh << 2);
        const int boff = (cb1 + (rl << 4)) ^ m1;
        *(unsigned short*)(H1 + boff) = f2bf(fmaxf(accA[r] + bv1n, 0.f));
        *(unsigned short*)(H1 + 16384 + boff) = f2bf(fmaxf(accB[r] + bv1n, 0.f));
      }
    }
    // b2f full preload for genre g+1 + bias (free under the barrier drain)
    {
      const unsigned short* const bp2gn = bp2 + ((size_t)(g + 1) << 15);
#pragma unroll
      for (int k = 0; k < 16; ++k) b2f[k] = *(const s8v*)(bp2gn + (k << 9));
      bv2 = b2[((g + 1) << 7) + gc2];
    }
    __syncthreads();
  }

  // ---- tail: GEMM2/3 for last genre (no GEMM1 to pipeline)
  {
    const int g = NG - 1;
    const unsigned short* const bp3g = bp3 + ((size_t)g << 14);
    f16v acc2a = zf16(), acc2b = zf16();
#pragma unroll
    for (int i = 0; i < 16; ++i) {
      s8v a2 = *(const s8v*)(H1 + (mt2 << 14) + (((i << 10) + lb) ^ KM(i)));
      if (i & 1) acc2b = mfma32(a2, b2f[i], acc2b);
      else       acc2a = mfma32(a2, b2f[i], acc2a);
    }
    s8v b3f[8];
#pragma unroll
    for (int k = 0; k < 8; ++k) b3f[k] = *(const s8v*)(bp3g + (k << 9));
    const float bv3 = b3[(g << 7) + gc2];
#pragma unroll
    for (int r = 0; r < 16; ++r) {
      const int rl = (r & 3) + ((r >> 2) << 3) + (lh << 2);
      float v = fmaxf(acc2a[r] + acc2b[r] + bv2, 0.f);
      *(unsigned short*)(H2 + (mt2 << 13) + ((cb2 + (rl << 4)) ^ m2)) = f2bf(v);
    }
    __syncthreads();

    f16v acc3a = zf16(), acc3b = zf16();
#pragma unroll
    for (int i = 0; i < 8; ++i) {
      s8v a3 = *(const s8v*)(H2 + (mt2 << 13) + (((i << 10) + lb) ^ KM(i)));
      if (i & 1) acc3b = mfma32(a3, b3f[i], acc3b);
      else       acc3a = mfma32(a3, b3f[i], acc3a);
    }
#pragma unroll
    for (int r = 0; r < 16; ++r) {
      const int rl = (r & 3) + ((r >> 2) << 3) + (lh << 2);
      racc[r] += WL[((mt2 << 5) + rl) * 20 + g] * (acc3a[r] + acc3b[r] + bv3);
    }
  }

  // prefetch GEMM4 depth-4 dual queue (flies across the barriers)
  s8v bq4[4][2];
#pragma unroll
  for (int k = 0; k < 4; ++k) {
    bq4[k][0] = *(const s8v*)(bp4a + (k << 9));
    bq4[k][1] = *(const s8v*)(bp4b + (k << 9));
  }
  __syncthreads();  // all GEMM3 H2 reads done
#pragma unroll
  for (int r = 0; r < 16; ++r) {
    const int rl = (r & 3) + ((r >> 2) << 3) + (lh << 2);
    *(unsigned short*)(H2 + (mt2 << 13) + ((cb2 + (rl << 4)) ^ m2)) = f2bf(racc[r]);
  }
  __syncthreads();

  // ---------- GEMM4: out = relu([X | ref] @ Wagg + bagg)  [64,512] ----------
  f16v acc4[2][2];
  acc4[0][0] = zf16(); acc4[0][1] = zf16();
  acc4[1][0] = zf16(); acc4[1][1] = zf16();
#pragma unroll
  for (int ks = 0; ks < 40; ++ks) {
    s8v bn0, bn1;
    if (ks < 36) {
      bn0 = *(const s8v*)(bp4a + ((ks + 4) << 9));
      bn1 = *(const s8v*)(bp4b + ((ks + 4) << 9));
    }
    s8v a0, a1;
    if (ks < 32) {
      a0 = *(const s8v*)(XT + (ks << 10) + (lane << 4));
      a1 = *(const s8v*)(XT + 32768 + (ks << 10) + (lane << 4));
    } else {
      const int hk = ks - 32;
      a0 = *(const s8v*)(H2 + (((hk << 10) + lb) ^ KM(hk)));
      a1 = *(const s8v*)(H2 + 8192 + (((hk << 10) + lb) ^ KM(hk)));
    }
    acc4[0][0] = mfma32(a0, bq4[ks & 3][0], acc4[0][0]);
    acc4[1][0] = mfma32(a1, bq4[ks & 3][0], acc4[1][0]);
    acc4[0][1] = mfma32(a0, bq4[ks & 3][1], acc4[0][1]);
    acc4[1][1] = mfma32(a1, bq4[ks & 3][1], acc4[1][1]);
    if (ks < 36) { bq4[ks & 3][0] = bn0; bq4[ks & 3][1] = bn1; }
  }
  {
    const float bv4a = bagg[(wid << 5) + l31];
    const float bv4b = bagg[((wid + 8) << 5) + l31];
#pragma unroll
    for (int mt = 0; mt < 2; ++mt)
#pragma unroll
      for (int r = 0; r < 16; ++r) {
        const int rl = (r & 3) + ((r >> 2) << 3) + (lh << 2);
        const size_t rbase = (size_t)(row0 + (mt << 5) + rl) << 9;
        out[rbase + (wid << 5) + l31] = fmaxf(acc4[mt][0][r] + bv4a, 0.f);
        out[rbase + ((wid + 8) << 5) + l31] = fmaxf(acc4[mt][1][r] + bv4b, 0.f);
      }
  }
}

// ---------------- workspace layout (bytes) ----------------
#define OFF_W1P   0u          // packed W1   : 4718592
#define OFF_W2P   4718592u    // packed W2   : 1179648
#define OFF_W3P   5898240u    // packed W3   : 589824
#define OFF_W4P   6488064u    // packed Wagg : 655360
#define OFF_WAP   7143424u    // packed Wa   : 32768   (end 7176192)

extern "C" void kernel_launch(void* const* d_in, const int* in_sizes, int n_in,
                              void* d_out, int out_size, void* d_ws, size_t ws_size,
                              hipStream_t stream) {
  const float* X    = (const float*)d_in[0];
  const float* GV   = (const float*)d_in[1];
  const float* W1   = (const float*)d_in[2];
  const float* b1   = (const float*)d_in[3];
  const float* W2   = (const float*)d_in[4];
  const float* b2   = (const float*)d_in[5];
  const float* W3   = (const float*)d_in[6];
  const float* b3   = (const float*)d_in[7];
  const float* Wa   = (const float*)d_in[8];
  const float* ba   = (const float*)d_in[9];
  const float* Wagg = (const float*)d_in[10];
  const float* bagg = (const float*)d_in[11];
  float* out = (float*)d_out;
  char* ws = (char*)d_ws;

  unsigned short* w1p = (unsigned short*)(ws + OFF_W1P);
  unsigned short* w2p = (unsigned short*)(ws + OFF_W2P);
  unsigned short* w3p = (unsigned short*)(ws + OFF_W3P);
  unsigned short* w4p = (unsigned short*)(ws + OFF_W4P);
  unsigned short* wap = (unsigned short*)(ws + OFF_WAP);

  k_pack<<<dim3(64, 18), 256, 0, stream>>>(W1, w1p, 512, 256);
  k_pack<<<dim3(16, 18), 256, 0, stream>>>(W2, w2p, 256, 128);
  k_pack<<<dim3(8, 18), 256, 0, stream>>>(W3, w3p, 128, 128);
  k_pack<<<dim3(160, 1), 256, 0, stream>>>(Wagg, w4p, 640, 512);
  k_packa<<<8, 256, 0, stream>>>(Wa, wap);
  k_main<<<256, 512, 0, stream>>>(X, GV, w1p, w2p, w3p, w4p, wap,
                                  b1, b2, b3, bagg, ba, out);
}